// Round 10
// baseline (167.013 us; speedup 1.0000x reference)
//
#include <hip/hip_runtime.h>
#include <hip/hip_bf16.h>

#define BATCH 16384
#define FIN   768
#define FOUT  512

#define BK 64
#define NT (FIN / BK)   // 12 K-iterations
#define BM 128          // batch rows per block -> 256 GEMM rows (stm+nstm)
#define BN 256          // feature cols per block (N-split x2)

typedef __attribute__((ext_vector_type(8))) short short8;
typedef __attribute__((ext_vector_type(4))) float floatx4;

// packed fp32x2 -> bf16x2, round-to-nearest-even (gfx940+ VOP3)
__device__ __forceinline__ unsigned int cvt_pk_bf16(float a, float b) {
    unsigned int r;
    asm("v_cvt_pk_bf16_f32 %0, %1, %2" : "=v"(r) : "v"(a), "v"(b));
    return r;
}

// async 16B global -> LDS DMA; HW scatters lane i to ldsbase + i*16
__device__ __forceinline__ void load_lds_16(const void* g, void* l) {
    __builtin_amdgcn_global_load_lds(
        (const __attribute__((address_space(1))) unsigned int*)g,
        (__attribute__((address_space(3))) unsigned int*)l,
        16, 0, 0);
}

// one-shot W1 fp32 -> bf16 (393216 elems, 8 per thread, 192 blocks)
__global__ __launch_bounds__(256) void cvt_w1(
    const float* __restrict__ W1, unsigned short* __restrict__ W1b)
{
    int base = (blockIdx.x * 256 + threadIdx.x) * 8;
    float4 a = *(const float4*)(W1 + base);
    float4 b = *(const float4*)(W1 + base + 4);
    uint4 o;
    o.x = cvt_pk_bf16(a.x, a.y); o.y = cvt_pk_bf16(a.z, a.w);
    o.z = cvt_pk_bf16(b.x, b.y); o.w = cvt_pk_bf16(b.z, b.w);
    *(uint4*)(W1b + base) = o;
}

// 256 blocks x 1024 threads, 1 block/CU. A NEVER TOUCHES LDS:
// wave tiles re-cut to 32x128 (16 waves = 8 row-bands x 2 col-halves) so A's
// intra-block reuse is only 2x -- each lane loads its own A fragment directly
// global->reg (2 dwordx4 fp32 per frag, cvt_pk at use; k-cols = quad*8, the
// exact frag layout previously read from LDS -- no swizzle, no conflicts).
// LDS holds only B: triple-buffered 3x32 KB, BK=64, R3-verified DMA+swizzle
// (slot = chunk ^ (row&7)). Per-iter barrier is ONLY {lgkmcnt(0); s_barrier}:
// issue order (B-DMA(t+2) first, then A(t) loads) + the compiler's counted
// vmem-wait before the A cvt guarantees B(t+1) retired before each barrier
// while B(t+2) rides across -- counted-vmcnt semantics with zero explicit
// vmcnt. Deleted vs R5 (47us champion): A publish VALU/ds_writes, A DMAs,
// 64 KB/iter LDS write traffic, half the ds_reads, the vmcnt drain.
// XCD-pair swizzle kept (FETCH halving, R4/R5-proven).
__global__ __launch_bounds__(1024, 4) void pn_gemm(
    const float* __restrict__ stm, const float* __restrict__ nstm,
    const unsigned short* __restrict__ W1b, const float* __restrict__ b1,
    const float* __restrict__ W2, float* __restrict__ P)
{
    __shared__ __align__(16) unsigned short Bs[3][256 * 64];  // 3 x 32 KB

    const int tid  = threadIdx.x;
    const int lane = tid & 63;
    const int wave = tid >> 6;    // 0..15
    const int wr   = wave >> 1;   // row band: GEMM rows wr*32 .. +31
    const int wc   = wave & 1;    // col half: cols wc*128 .. +127 (within BN)
    const int quad = lane >> 4;
    const int l16  = lane & 15;

    // XCD-pair swizzle (bijective: 256 blocks, 8 XCDs, chunk 32): the
    // (bm, n_idx=0/1) pair gets consecutive sbids -> same XCD -> shared L2.
    const int sbid  = (blockIdx.x & 7) * 32 + (blockIdx.x >> 3);
    const int bm    = sbid >> 1;
    const int n_idx = sbid & 1;
    const int b0    = bm * BM;        // batch rows owned by this block
    const int n0    = n_idx * BN;     // feature cols owned by this block

    // ---- A direct-load pointers: frag rows m = wr*32 + mi*16 + l16.
    // Lane supplies A[row=l16-of-frag][k = quad*8 .. +7] per MFMA -- so the
    // per-lane base is row-ptr + quad*8; per (t,kk) add t*64 + kk*32.
    // wr<4 -> GEMM rows 0..127 = stm; wr>=4 -> nstm (wave-uniform).
    const float* aPtr0;
    const float* aPtr1;
    {
        int m0 = wr * 32 + 0 * 16 + l16;
        int m1 = wr * 32 + 1 * 16 + l16;
        aPtr0 = ((m0 < BM) ? stm + (size_t)(b0 + m0) * FIN
                           : nstm + (size_t)(b0 + m0 - BM) * FIN) + quad * 8;
        aPtr1 = ((m1 < BM) ? stm + (size_t)(b0 + m1) * FIN
                           : nstm + (size_t)(b0 + m1 - BM) * FIN) + quad * 8;
    }

    // ---- B staging (R3-verified BK=64): 2 DMA instrs/wave, J = wave*2+i
    // covers W1 rows J*8..+7. DMA: lane l -> row J*8+(l>>3), 16B-slot l&7;
    // source chunk pre-swizzled (l&7)^(l>>3) so LDS slot = chunk ^ (row&7).
    const int brow = lane >> 3;
    const int bch  = (lane & 7) ^ brow;
    const unsigned short* bSrc0 =
        W1b + (size_t)(n0 + (wave * 2 + 0) * 8 + brow) * FIN + bch * 8;
    const unsigned short* bSrc1 =
        W1b + (size_t)(n0 + (wave * 2 + 1) * 8 + brow) * FIN + bch * 8;
    const int bDst0 = (wave * 2 + 0) * 512;   // short index into Bs[buf]
    const int bDst1 = (wave * 2 + 1) * 512;

    floatx4 acc[2][8];
    #pragma unroll
    for (int i = 0; i < 2; ++i)
        #pragma unroll
        for (int j = 0; j < 8; ++j)
            acc[i][j] = (floatx4)0.0f;

    // ---- prologue: B(0), B(1) DMA groups; drain B(0) (keep B(1) flying)
    load_lds_16(bSrc0,      &Bs[0][bDst0]);
    load_lds_16(bSrc1,      &Bs[0][bDst1]);
    load_lds_16(bSrc0 + BK, &Bs[1][bDst0]);
    load_lds_16(bSrc1 + BK, &Bs[1][bDst1]);
    __builtin_amdgcn_sched_barrier(0);
    asm volatile("s_waitcnt vmcnt(2) lgkmcnt(0)" ::: "memory");
    __builtin_amdgcn_s_barrier();
    __builtin_amdgcn_sched_barrier(0);

    int bc = 0;   // Bs buffer holding tile t
    for (int t = 0; t < NT; ++t) {
        // issue B-DMA(t+2) FIRST (oldest of this iter's vmem); its buffer's
        // previous readers drained at the end-barrier of iter t-1.
        if (t + 2 < NT) {
            int bp = bc + 2; if (bp >= 3) bp -= 3;
            const int kn2 = (t + 2) * BK;
            load_lds_16(bSrc0 + kn2, &Bs[bp][bDst0]);
            load_lds_16(bSrc1 + kn2, &Bs[bp][bDst1]);
        }

        // two K=32 halves; per half: 4 A global loads + 8 cvt_pk + 8 ds_read
        // + 16 MFMA. The compiler's vmem-wait before each cvt (younger
        // in-flight: at most the other half's A loads) retires B(t+1).
        #pragma unroll
        for (int kk = 0; kk < 2; ++kk) {
            const int koff = t * BK + kk * 32;
            const int c    = kk * 4 + quad;   // k-chunk index 0..7

            // A frags (global, fp32 -> bf16)
            short8 af0, af1;
            {
                float4 lo = *(const float4*)(aPtr0 + koff);
                float4 hi = *(const float4*)(aPtr0 + koff + 4);
                uint4 o;
                o.x = cvt_pk_bf16(lo.x, lo.y); o.y = cvt_pk_bf16(lo.z, lo.w);
                o.z = cvt_pk_bf16(hi.x, hi.y); o.w = cvt_pk_bf16(hi.z, hi.w);
                af0 = *(short8*)&o;
            }
            {
                float4 lo = *(const float4*)(aPtr1 + koff);
                float4 hi = *(const float4*)(aPtr1 + koff + 4);
                uint4 o;
                o.x = cvt_pk_bf16(lo.x, lo.y); o.y = cvt_pk_bf16(lo.z, lo.w);
                o.z = cvt_pk_bf16(hi.x, hi.y); o.w = cvt_pk_bf16(hi.z, hi.w);
                af1 = *(short8*)&o;
            }

            // B frags in two halves of 4 (register cap: bfr[4] = 16 VGPR)
            #pragma unroll
            for (int nh = 0; nh < 2; ++nh) {
                short8 bfr[4];
                #pragma unroll
                for (int j = 0; j < 4; ++j) {
                    const int n = wc * 128 + (nh * 4 + j) * 16 + l16;
                    bfr[j] = *(const short8*)(
                        &Bs[bc][n * 64 + ((c ^ (n & 7)) * 8)]);
                }
                #pragma unroll
                for (int j = 0; j < 4; ++j) {
                    acc[0][nh * 4 + j] = __builtin_amdgcn_mfma_f32_16x16x32_bf16(
                        af0, bfr[j], acc[0][nh * 4 + j], 0, 0, 0);
                    acc[1][nh * 4 + j] = __builtin_amdgcn_mfma_f32_16x16x32_bf16(
                        af1, bfr[j], acc[1][nh * 4 + j], 0, 0, 0);
                }
            }
        }

        bc = (bc == 2) ? 0 : bc + 1;

        // end barrier: ONLY lgkm drain (publishes nothing; protects the
        // buffer B(t+3) will overwrite; B-DMA prefetches ride across).
        __builtin_amdgcn_sched_barrier(0);
        asm volatile("s_waitcnt lgkmcnt(0)" ::: "memory");
        __builtin_amdgcn_s_barrier();
        __builtin_amdgcn_sched_barrier(0);
    }

    // ---- fused epilogue. C/D layout: col = lane&15, row = quad*4 + reg.
    // GEMM rows 0-127 (wr 0..3) = stm -> W2[0..511];
    // rows 128-255 (wr 4..7) = nstm -> W2[512..1023]. wr is wave-uniform.
    float b1v[8], w2v[8];
    const float* w2base = (wr < 4) ? W2 : W2 + FOUT;
    #pragma unroll
    for (int ni = 0; ni < 8; ++ni) {
        int col = n0 + wc * 128 + ni * 16 + l16;
        b1v[ni] = b1[col];
        w2v[ni] = w2base[col];
    }

    float* Epi = (float*)Bs;         // [256 rows][2 wave-cols] partials (2 KB)

    #pragma unroll
    for (int mi = 0; mi < 2; ++mi) {
        #pragma unroll
        for (int r = 0; r < 4; ++r) {
            float s = 0.0f;
            #pragma unroll
            for (int ni = 0; ni < 8; ++ni) {
                float h = acc[mi][ni][r] + b1v[ni];
                h = fminf(fmaxf(h, 0.0f), 1.0f);
                s += h * w2v[ni];
            }
            s += __shfl_xor(s, 1);
            s += __shfl_xor(s, 2);
            s += __shfl_xor(s, 4);
            s += __shfl_xor(s, 8);
            if (l16 == 0) {
                Epi[(wr * 32 + mi * 16 + quad * 4 + r) * 2 + wc] = s;
            }
        }
    }
    __syncthreads();

    // batch row i partial over this block's 256 features =
    // stm-row i partials (rows 0-127) + nstm-row i partials (128-255)
    if (tid < BM) {
        float x = Epi[tid * 2] + Epi[tid * 2 + 1]
                + Epi[(tid + BM) * 2] + Epi[(tid + BM) * 2 + 1];
        P[n_idx * BATCH + b0 + tid] = x;
    }
}

// sum the two N-half partials + bias, sigmoid
__global__ __launch_bounds__(256) void finish(
    const float* __restrict__ P, const float* __restrict__ b2,
    float* __restrict__ out)
{
    int i = blockIdx.x * 256 + threadIdx.x;
    float x = b2[0] + P[i] + P[BATCH + i];
    out[i] = 1.0f / (1.0f + expf(-x));
}

extern "C" void kernel_launch(void* const* d_in, const int* in_sizes, int n_in,
                              void* d_out, int out_size, void* d_ws, size_t ws_size,
                              hipStream_t stream)
{
    (void)in_sizes; (void)n_in; (void)out_size; (void)ws_size;
    const float* stm  = (const float*)d_in[0];
    const float* nstm = (const float*)d_in[1];
    const float* W1   = (const float*)d_in[2];
    const float* b1   = (const float*)d_in[3];
    const float* W2   = (const float*)d_in[4];
    const float* b2   = (const float*)d_in[5];
    float* out = (float*)d_out;
    unsigned short* W1b = (unsigned short*)d_ws;           // bf16 W1 (768 KB)
    float* P = (float*)((char*)d_ws + FOUT * FIN * 2);     // partials (128 KB)

    cvt_w1<<<dim3((FOUT * FIN) / (256 * 8)), dim3(256), 0, stream>>>(W1, W1b);
    pn_gemm<<<dim3((BATCH / BM) * 2), dim3(1024), 0, stream>>>(
        stm, nstm, W1b, b1, W2, P);
    finish<<<dim3(BATCH / 256), dim3(256), 0, stream>>>(P, b2, out);
}

// Round 11
// 153.078 us; speedup vs baseline: 1.0910x; 1.0910x over previous
//
#include <hip/hip_runtime.h>
#include <hip/hip_bf16.h>

#define BATCH 16384
#define FIN   768
#define FOUT  512

#define BK 64
#define NT (FIN / BK)   // 12 K-iterations
#define BM 128          // batch rows per block -> 256 GEMM rows (stm+nstm)
#define BN 256          // feature cols per block (N-split x2)

typedef __attribute__((ext_vector_type(8))) short short8;
typedef __attribute__((ext_vector_type(16))) float floatx16;

// packed fp32x2 -> bf16x2, round-to-nearest-even (gfx940+ VOP3)
__device__ __forceinline__ unsigned int cvt_pk_bf16(float a, float b) {
    unsigned int r;
    asm("v_cvt_pk_bf16_f32 %0, %1, %2" : "=v"(r) : "v"(a), "v"(b));
    return r;
}

// async 16B global -> LDS DMA; HW scatters lane i to ldsbase + i*16
__device__ __forceinline__ void load_lds_16(const void* g, void* l) {
    __builtin_amdgcn_global_load_lds(
        (const __attribute__((address_space(1))) unsigned int*)g,
        (__attribute__((address_space(3))) unsigned int*)l,
        16, 0, 0);
}

// Raw barrier with COUNTED vmcnt (T4): allow the 2 B-DMAs for tile t+2 to
// stay in flight across the barrier; guarantees (in-order vmem retirement)
// that tile t+1's DMAs -- issued a full iteration earlier -- have landed.
// lgkmcnt(0) publishes this wave's A ds_writes / drains its frag ds_reads.
#define BAR_VM2() do {                                               \
    __builtin_amdgcn_sched_barrier(0);                               \
    asm volatile("s_waitcnt vmcnt(2) lgkmcnt(0)" ::: "memory");      \
    __builtin_amdgcn_s_barrier();                                    \
    __builtin_amdgcn_sched_barrier(0);                               \
} while (0)

// one-shot W1 fp32 -> bf16 (393216 elems, 8 per thread, 192 blocks)
__global__ __launch_bounds__(256) void cvt_w1(
    const float* __restrict__ W1, unsigned short* __restrict__ W1b)
{
    int base = (blockIdx.x * 256 + threadIdx.x) * 8;
    float4 a = *(const float4*)(W1 + base);
    float4 b = *(const float4*)(W1 + base + 4);
    uint4 o;
    o.x = cvt_pk_bf16(a.x, a.y); o.y = cvt_pk_bf16(a.z, a.w);
    o.z = cvt_pk_bf16(b.x, b.y); o.w = cvt_pk_bf16(b.z, b.w);
    *(uint4*)(W1b + base) = o;
}

// 256 blocks x 1024 threads, 1 block/CU (160 KB LDS). Identical to the
// verified R5 champion (16 waves x 64x64 tiles, BK=64, B triple-buffer with
// depth-2 DMA + vmcnt(2) counted barrier, XCD-pair swizzle) EXCEPT the MFMA
// shape: 16x16x32 -> 32x32x16 (m119: 2495 vs 2176 TF ceiling). At the fixed
// 64x64 wave tile this halves MFMA instructions (16 vs 32 per BK=64) at the
// SAME ds_read count (16 b128), SAME acc registers (2x2x16 = 64), same
// swizzle math (16B-chunk slot = c ^ (row&7); 32-lane groups spread evenly
// over all 32 banks -- 8-phase minimum, no extra serialization).
// Frag mapping (32x32x16): A lane = row l&31, k = (l>>5)*8 + j;
// B lane = col l&31, k = (l>>5)*8 + j.
// C/D (m74/m101-verified): col = lane&31, row = (r&3) + 8*(r>>2) + 4*(l>>5).
__global__ __launch_bounds__(1024, 4) void pn_gemm(
    const float* __restrict__ stm, const float* __restrict__ nstm,
    const unsigned short* __restrict__ W1b, const float* __restrict__ b1,
    const float* __restrict__ W2, float* __restrict__ P)
{
    __shared__ __align__(16) unsigned short As[2][256 * 64];  // 2 x 32 KB
    __shared__ __align__(16) unsigned short Bs[3][256 * 64];  // 3 x 32 KB

    const int tid  = threadIdx.x;
    const int lane = tid & 63;
    const int wave = tid >> 6;    // 0..15
    const int wr   = wave >> 2;   // row tile: GEMM rows wr*64 .. +63
    const int wc   = wave & 3;    // col tile: cols wc*64 .. +63 (within BN)
    const int l31  = lane & 31;
    const int hi   = lane >> 5;

    // XCD-pair swizzle (bijective: 256 blocks, 8 XCDs, chunk 32): the
    // (bm, n_idx=0/1) pair gets consecutive sbids -> same XCD -> shared L2.
    const int sbid  = (blockIdx.x & 7) * 32 + (blockIdx.x >> 3);
    const int bm    = sbid >> 1;
    const int n_idx = sbid & 1;
    const int b0    = bm * BM;        // batch rows owned by this block
    const int n0    = n_idx * BN;     // feature cols owned by this block

    // ---- A staging: thread covers row arow, chunks ac and ac+4 (16 fp32)
    const int arow = tid >> 2;        // 0..255
    const int ac   = tid & 3;         // low chunk; high chunk = ac+4
    const float* aSrc =
        ((arow < BM) ? stm  + (size_t)(b0 + arow) * FIN
                     : nstm + (size_t)(b0 + arow - BM) * FIN);
    const int aOffLo = arow * 64 + ((ac       ^ (arow & 7)) * 8);  // swizzled
    const int aOffHi = arow * 64 + (((ac + 4) ^ (arow & 7)) * 8);

    // ---- B staging: 2 DMA instrs/wave, J = wave*2+i covers rows J*8..+7.
    // DMA writes lane l -> base + l*16 (row l>>3, slot l&7); source chunk is
    // pre-swizzled so LDS holds slot = chunk ^ (row&7).
    const int brow = lane >> 3;                 // row within 8-group
    const int bch  = (lane & 7) ^ brow;         // swizzled SOURCE chunk
    const unsigned short* bSrc =
        W1b + (size_t)(n0 + brow) * FIN + bch * 8;

    floatx16 acc[2][2];
    #pragma unroll
    for (int i = 0; i < 2; ++i)
        #pragma unroll
        for (int j = 0; j < 2; ++j)
            acc[i][j] = (floatx16)0.0f;

    // ---- prologue: B(0), then A(0) regs, then B(1) (issue order matters:
    // publish(0)'s A-reg wait implies B(0) retired; B(1) stays outstanding)
    #pragma unroll
    for (int i = 0; i < 2; ++i) {
        const int J = wave * 2 + i;
        load_lds_16(bSrc + (size_t)(J * 8) * FIN, &Bs[0][J * 512]);
    }
    float4 ap0 = *(const float4*)(aSrc + ac * 8);
    float4 ap1 = *(const float4*)(aSrc + ac * 8 + 4);
    float4 ap2 = *(const float4*)(aSrc + (ac + 4) * 8);
    float4 ap3 = *(const float4*)(aSrc + (ac + 4) * 8 + 4);
    #pragma unroll
    for (int i = 0; i < 2; ++i) {
        const int J = wave * 2 + i;
        load_lds_16(bSrc + (size_t)(J * 8) * FIN + BK, &Bs[1][J * 512]);
    }

    int bc = 0;   // Bs buffer holding tile t
    for (int t = 0; t < NT; ++t) {
        const int cur = t & 1;

        // publish A(t) (regs loaded last iter; As[cur] reads drained at barrier t-1)
        {
            uint4 o1, o2;
            o1.x = cvt_pk_bf16(ap0.x, ap0.y); o1.y = cvt_pk_bf16(ap0.z, ap0.w);
            o1.z = cvt_pk_bf16(ap1.x, ap1.y); o1.w = cvt_pk_bf16(ap1.z, ap1.w);
            o2.x = cvt_pk_bf16(ap2.x, ap2.y); o2.y = cvt_pk_bf16(ap2.z, ap2.w);
            o2.z = cvt_pk_bf16(ap3.x, ap3.y); o2.w = cvt_pk_bf16(ap3.z, ap3.w);
            *(uint4*)(&As[cur][aOffLo]) = o1;
            *(uint4*)(&As[cur][aOffHi]) = o2;
        }
        BAR_VM2();   // B(t) guaranteed landed; B(t+1) DMAs ride across

        // issue staging — A-loads(t+1) FIRST, then B-DMA(t+2) (newest 2)
        if (t + 1 < NT) {
            const int kn = (t + 1) * BK;
            ap0 = *(const float4*)(aSrc + kn + ac * 8);
            ap1 = *(const float4*)(aSrc + kn + ac * 8 + 4);
            ap2 = *(const float4*)(aSrc + kn + (ac + 4) * 8);
            ap3 = *(const float4*)(aSrc + kn + (ac + 4) * 8 + 4);
        }
        if (t + 2 < NT) {
            int bp = bc + 2; if (bp >= 3) bp -= 3;
            const size_t kn2 = (size_t)(t + 2) * BK;
            #pragma unroll
            for (int i = 0; i < 2; ++i) {
                const int J = wave * 2 + i;
                load_lds_16(bSrc + (size_t)(J * 8) * FIN + kn2,
                            &Bs[bp][J * 512]);
            }
        }

        // compute tile t: 4 K=16 steps; per step 4 ds_read_b128 + 4 MFMA
        #pragma unroll
        for (int ks = 0; ks < 4; ++ks) {
            const int c = ks * 2 + hi;   // 16B-chunk index 0..7
            const int m0 = wr * 64 + l31;
            const int m1 = m0 + 32;
            const int nn0 = wc * 64 + l31;
            const int nn1 = nn0 + 32;
            short8 a0 = *(const short8*)(&As[cur][m0 * 64 + ((c ^ (m0 & 7)) * 8)]);
            short8 a1 = *(const short8*)(&As[cur][m1 * 64 + ((c ^ (m1 & 7)) * 8)]);
            short8 bb0 = *(const short8*)(&Bs[bc][nn0 * 64 + ((c ^ (nn0 & 7)) * 8)]);
            short8 bb1 = *(const short8*)(&Bs[bc][nn1 * 64 + ((c ^ (nn1 & 7)) * 8)]);
            acc[0][0] = __builtin_amdgcn_mfma_f32_32x32x16_bf16(
                a0, bb0, acc[0][0], 0, 0, 0);
            acc[0][1] = __builtin_amdgcn_mfma_f32_32x32x16_bf16(
                a0, bb1, acc[0][1], 0, 0, 0);
            acc[1][0] = __builtin_amdgcn_mfma_f32_32x32x16_bf16(
                a1, bb0, acc[1][0], 0, 0, 0);
            acc[1][1] = __builtin_amdgcn_mfma_f32_32x32x16_bf16(
                a1, bb1, acc[1][1], 0, 0, 0);
        }

        bc = (bc == 2) ? 0 : bc + 1;
    }

    // ---- fused epilogue. 32x32 C/D layout: col = lane&31,
    // row = (r&3) + 8*(r>>2) + 4*hi, r in [0,16).
    // GEMM rows 0-127 (wr 0,1) = stm -> W2[0..511];
    // rows 128-255 (wr 2,3) = nstm -> W2[512..1023]. wr is wave-uniform.
    float b1v[2], w2v[2];
    const float* w2base = (wr < 2) ? W2 : W2 + FOUT;
    #pragma unroll
    for (int ni = 0; ni < 2; ++ni) {
        int col = n0 + wc * 64 + ni * 32 + l31;
        b1v[ni] = b1[col];
        w2v[ni] = w2base[col];
    }

    __syncthreads();                 // full drain; reuse As
    float* Epi = (float*)As;         // [256 rows][4 wave-cols] partials (4 KB)

    #pragma unroll
    for (int mi = 0; mi < 2; ++mi) {
        #pragma unroll
        for (int r = 0; r < 16; ++r) {
            float s = 0.0f;
            #pragma unroll
            for (int ni = 0; ni < 2; ++ni) {
                float h = acc[mi][ni][r] + b1v[ni];
                h = fminf(fmaxf(h, 0.0f), 1.0f);
                s += h * w2v[ni];
            }
            s += __shfl_xor(s, 1);
            s += __shfl_xor(s, 2);
            s += __shfl_xor(s, 4);
            s += __shfl_xor(s, 8);
            s += __shfl_xor(s, 16);
            if (l31 == 0) {
                const int row = wr * 64 + mi * 32 + (r & 3) + 8 * (r >> 2) + 4 * hi;
                Epi[row * 4 + wc] = s;
            }
        }
    }
    __syncthreads();

    // batch row i partial over this block's 256 features =
    // stm-row i partials (rows 0-127) + nstm-row i partials (128-255)
    if (tid < BM) {
        float x = 0.0f;
        #pragma unroll
        for (int j = 0; j < 4; ++j)
            x += Epi[tid * 4 + j] + Epi[(tid + BM) * 4 + j];
        P[n_idx * BATCH + b0 + tid] = x;
    }
}

// sum the two N-half partials + bias, sigmoid
__global__ __launch_bounds__(256) void finish(
    const float* __restrict__ P, const float* __restrict__ b2,
    float* __restrict__ out)
{
    int i = blockIdx.x * 256 + threadIdx.x;
    float x = b2[0] + P[i] + P[BATCH + i];
    out[i] = 1.0f / (1.0f + expf(-x));
}

extern "C" void kernel_launch(void* const* d_in, const int* in_sizes, int n_in,
                              void* d_out, int out_size, void* d_ws, size_t ws_size,
                              hipStream_t stream)
{
    (void)in_sizes; (void)n_in; (void)out_size; (void)ws_size;
    const float* stm  = (const float*)d_in[0];
    const float* nstm = (const float*)d_in[1];
    const float* W1   = (const float*)d_in[2];
    const float* b1   = (const float*)d_in[3];
    const float* W2   = (const float*)d_in[4];
    const float* b2   = (const float*)d_in[5];
    float* out = (float*)d_out;
    unsigned short* W1b = (unsigned short*)d_ws;           // bf16 W1 (768 KB)
    float* P = (float*)((char*)d_ws + FOUT * FIN * 2);     // partials (128 KB)

    cvt_w1<<<dim3((FOUT * FIN) / (256 * 8)), dim3(256), 0, stream>>>(W1, W1b);
    pn_gemm<<<dim3((BATCH / BM) * 2), dim3(1024), 0, stream>>>(
        stm, nstm, W1b, b1, W2, P);
    finish<<<dim3(BATCH / 256), dim3(256), 0, stream>>>(P, b2, out);
}